// Round 2
// baseline (330.220 us; speedup 1.0000x reference)
//
#include <hip/hip_runtime.h>

#define BATCH 131072
#define UNITS 512
#define DIM   64
#define BM    16     // rows per block; all 4 waves cooperate on one 16-row tile
#define STF   516    // st row stride (floats): 516%32==4 -> 2-way banks (free); 2064B row, 16B-aligned

typedef __attribute__((ext_vector_type(8))) short  short8;
typedef __attribute__((ext_vector_type(4))) float  floatx4;

static __device__ __forceinline__ unsigned short f32_to_bf16(float f) {
    union { float f; unsigned int u; } c; c.f = f;
    unsigned int u = c.u;
    unsigned int r = u + 0x7fffu + ((u >> 16) & 1u);   // round-nearest-even
    return (unsigned short)(r >> 16);
}

// Convert w [512][64] fp32 -> bf16, and per-row sum of squares.
__global__ __launch_bounds__(256) void prep_w_kernel(
    const float* __restrict__ w,
    unsigned short* __restrict__ wb,
    float* __restrict__ wsq)
{
    const int u = blockIdx.x * 4 + (threadIdx.x >> 6);   // one wave per w-row
    const int d = threadIdx.x & 63;
    float v = w[u * DIM + d];
    wb[u * DIM + d] = f32_to_bf16(v);
    float s = v * v;
    #pragma unroll
    for (int o = 32; o > 0; o >>= 1) s += __shfl_xor(s, o);
    if (d == 0) wsq[u] = s;
}

// dist[b,u] = ||x_b||^2 + ||w_u||^2 - 2 * x_b . w_u
//
// Store-pattern-first design: the rocclr fill proves 6.5 TB/s write BW needs
// only one thing — each wave store instruction = ONE contiguous aligned 1 KiB
// segment (it does so at 9.9% occupancy, 4.9% VALUBusy). Previous kernels
// fragmented each 1 KiB store into 4x256B (125us) or 16x64B (160us) row
// segments and ran at ~2.5 TB/s effective. Here a block computes a FULL
// 16-row x 512-col output tile into LDS (bank-pad 516), then drains whole
// rows: every store = 1 KiB contiguous, 1 KiB-aligned, nontemporal.
// nt keeps the 256 MiB output stream from evicting wb (64 KB, L2-resident).
__global__ __launch_bounds__(256, 4) void dist_kernel(
    const float* __restrict__ x,
    const unsigned short* __restrict__ wb,
    const float* __restrict__ wsq,
    float* __restrict__ out)
{
    __shared__ float wsq_s[UNITS];                 // 2 KB
    __shared__ __align__(16) float st[BM][STF];    // 33 KB -> 4 blocks/CU

    const int tid  = threadIdx.x;
    const int row0 = blockIdx.x * BM;

    wsq_s[tid]       = wsq[tid];
    wsq_s[tid + 256] = wsq[tid + 256];

    const int wave = tid >> 6;
    const int lane = tid & 63;
    const int l15  = lane & 15;
    const int quad = lane >> 4;

    // ---- A-frag straight from global (verified layout):
    //      A[m = l15][k = quad*8 + j], halves k<32 / k>=32 ----
    short8 a[2];
    float  xs;
    {
        const float* xr = x + (size_t)(row0 + l15) * DIM;
        float v[16];
        *(float4*)&v[0]  = *(const float4*)(xr + quad * 8);
        *(float4*)&v[4]  = *(const float4*)(xr + quad * 8 + 4);
        *(float4*)&v[8]  = *(const float4*)(xr + 32 + quad * 8);
        *(float4*)&v[12] = *(const float4*)(xr + 32 + quad * 8 + 4);
        float s = 0.f;
        unsigned short p[16];
        #pragma unroll
        for (int i = 0; i < 16; ++i) { s += v[i] * v[i]; p[i] = f32_to_bf16(v[i]); }
        a[0] = *(short8*)&p[0];
        a[1] = *(short8*)&p[8];
        // lanes sharing l15 (4 quads) jointly hold all 64 elems of row l15
        s += __shfl_xor(s, 16);
        s += __shfl_xor(s, 32);
        xs = s;                                    // ||x_row(l15)||^2
    }
    // xsq for the rows this lane's acc covers: m = quad*4 + i
    float xsm[4];
    #pragma unroll
    for (int i = 0; i < 4; ++i) xsm[i] = __shfl(xs, quad * 4 + i);

    __syncthreads();                               // wsq_s ready

    const short8* wv = (const short8*)wb;          // w rows as groups of 8 bf16

    // each wave owns 2 of the 8 u-groups (64 cols each)
    #pragma unroll
    for (int g = 0; g < 2; ++g) {
        const int colb = (wave * 2 + g) * 64;

        short8 b2[4][2];
        float  wq[4];
        #pragma unroll
        for (int t = 0; t < 4; ++t) {
            const short8* bp = wv + (size_t)(colb + t * 16 + l15) * 8;
            b2[t][0] = bp[quad];
            b2[t][1] = bp[quad + 4];
            wq[t]    = wsq_s[colb + t * 16 + l15];
        }

        #pragma unroll
        for (int t = 0; t < 4; ++t) {
            floatx4 acc = floatx4{0.f, 0.f, 0.f, 0.f};
            acc = __builtin_amdgcn_mfma_f32_16x16x32_bf16(a[0], b2[t][0], acc, 0, 0, 0);
            acc = __builtin_amdgcn_mfma_f32_16x16x32_bf16(a[1], b2[t][1], acc, 0, 0, 0);

            // C/D layout (verified): row m = quad*4+i, col u = colb + t*16 + l15
            // LDS write banks: (quad*4*516 + l15)%32 -> 2-way only (free)
            #pragma unroll
            for (int i = 0; i < 4; ++i)
                st[quad * 4 + i][colb + t * 16 + l15] =
                    xsm[i] + wq[t] - 2.0f * acc[i];
        }
    }

    __syncthreads();                               // full 16x512 tile staged

    // ---- drain: wave stores rows wave*4 .. wave*4+3, each row = 2 x 1 KiB
    //      fully-contiguous aligned wave-store instructions (fill pattern) ----
    #pragma unroll
    for (int j = 0; j < 4; ++j) {
        const int r = wave * 4 + j;
        const float* src = &st[r][0];
        float* dst = out + (size_t)(row0 + r) * UNITS;
        #pragma unroll
        for (int h = 0; h < 2; ++h) {
            const floatx4 vv = *(const floatx4*)(src + h * 256 + lane * 4);
            __builtin_nontemporal_store(vv, (floatx4*)(dst + h * 256 + lane * 4));
        }
    }
}

extern "C" void kernel_launch(void* const* d_in, const int* in_sizes, int n_in,
                              void* d_out, int out_size, void* d_ws, size_t ws_size,
                              hipStream_t stream) {
    const float* x = (const float*)d_in[0];
    const float* w = (const float*)d_in[1];
    float* out = (float*)d_out;

    unsigned short* wb  = (unsigned short*)d_ws;                       // 64 KB
    float*          wsq = (float*)((char*)d_ws + UNITS * DIM * 2);     // 2 KB

    prep_w_kernel<<<UNITS / 4, 256, 0, stream>>>(w, wb, wsq);
    dist_kernel<<<BATCH / BM, 256, 0, stream>>>(x, wb, wsq, out);
}

// Round 3
// 299.207 us; speedup vs baseline: 1.1037x; 1.1037x over previous
//
#include <hip/hip_runtime.h>

#define BATCH 131072
#define UNITS 512
#define DIM   64
#define BM    128
#define STRIDE 68   // floats; 68%32==4 -> 4-aligned bank groups, 16B-aligned rows

typedef __attribute__((ext_vector_type(8))) short  short8;
typedef __attribute__((ext_vector_type(4))) float  floatx4;

static __device__ __forceinline__ unsigned short f32_to_bf16(float f) {
    union { float f; unsigned int u; } c; c.f = f;
    unsigned int u = c.u;
    unsigned int r = u + 0x7fffu + ((u >> 16) & 1u);   // round-nearest-even
    return (unsigned short)(r >> 16);
}

// Convert w [512][64] fp32 -> bf16, and per-row sum of squares.
__global__ __launch_bounds__(256) void prep_w_kernel(
    const float* __restrict__ w,
    unsigned short* __restrict__ wb,
    float* __restrict__ wsq)
{
    const int u = blockIdx.x * 4 + (threadIdx.x >> 6);   // one wave per w-row
    const int d = threadIdx.x & 63;
    float v = w[u * DIM + d];
    wb[u * DIM + d] = f32_to_bf16(v);
    float s = v * v;
    #pragma unroll
    for (int o = 32; o > 0; o >>= 1) s += __shfl_xor(s, o);
    if (d == 0) wsq[u] = s;
}

// dist[b,u] = ||x_b||^2 + ||w_u||^2 - 2 * x_b . w_u
//
// EXACT copy of the best-measured kernel (293.9 us session baseline) with
// ONE variable flipped: output stores are PLAIN, not nontemporal.
// A/B rationale: R1 (16x64B segments) and R2 (1x1024B segments) timed
// identically (+35us vs this structure), killing the store-segmentation
// theory. The rocclr fill sustains 6.5 TB/s with regular stores at 3
// waves/CU; all our kernels used nt and none exceeded ~2.5 TB/s effective
// write. Hypothesis: nt (write-around) limits write-combining depth on
// gfx950. wb is 64 KB and re-read constantly -> survives L2 LRU without nt
// protection.
__global__ __launch_bounds__(256) void dist_kernel(
    const float* __restrict__ x,
    const unsigned short* __restrict__ wb,
    const float* __restrict__ wsq,
    float* __restrict__ out)
{
    __shared__ __align__(16) unsigned short xb[BM][DIM];   // 16 KB
    __shared__ float xsq[BM];
    __shared__ float wsq_s[UNITS];
    __shared__ __align__(16) float st[4][16][STRIDE];      // 17.4 KB, per-wave chunks

    const int tid  = threadIdx.x;
    const int row0 = blockIdx.x * BM;

    // stage wsq into LDS
    wsq_s[tid]       = wsq[tid];
    wsq_s[tid + 256] = wsq[tid + 256];

    // ---- stage x tile: fp32 -> bf16 into LDS, fused row sum-of-squares ----
    #pragma unroll
    for (int half = 0; half < BM / 64; ++half) {
        const int r = half * 64 + (tid >> 2);
        const int q = tid & 3;
        const float4* src = (const float4*)(x + (size_t)(row0 + r) * DIM + q * 16);
        float v[16];
        *(float4*)&v[0]  = src[0];
        *(float4*)&v[4]  = src[1];
        *(float4*)&v[8]  = src[2];
        *(float4*)&v[12] = src[3];
        float s = 0.f;
        unsigned short p[16];
        #pragma unroll
        for (int i = 0; i < 16; ++i) { s += v[i] * v[i]; p[i] = f32_to_bf16(v[i]); }
        uint4* dst = (uint4*)&xb[r][q * 16];
        dst[0] = *(uint4*)&p[0];
        dst[1] = *(uint4*)&p[8];
        s += __shfl_xor(s, 1);
        s += __shfl_xor(s, 2);
        if (q == 0) xsq[r] = s;
    }
    __syncthreads();

    const int wave = tid >> 6;
    const int lane = tid & 63;
    const int l15  = lane & 15;
    const int quad = lane >> 4;
    const int mrow = wave * 32;

    // A-frags (verified): A[m = lane&15][k = quad*8 + j], two k-halves of 32
    short8 a[2][2];
    float  xs[2][4];
    #pragma unroll
    for (int mf = 0; mf < 2; ++mf) {
        const short8* ar = (const short8*)&xb[mrow + mf * 16 + l15][0];
        a[mf][0] = ar[quad];
        a[mf][1] = ar[quad + 4];
        #pragma unroll
        for (int i = 0; i < 4; ++i)
            xs[mf][i] = xsq[mrow + mf * 16 + quad * 4 + i];
    }

    const short8* wv  = (const short8*)wb;   // w rows as groups of 8 bf16
    float*        stw = &st[wave][0][0];     // wave-private stage

    for (int gu = 0; gu < 8; ++gu) {         // 8 groups of 64 cols
        const int colb = gu * 64;

        // B-frags for 4 col-tiles x 2 k-halves (verified layout)
        short8 b[4][2];
        float  wq[4];
        #pragma unroll
        for (int t = 0; t < 4; ++t) {
            const short8* bp = wv + (size_t)(colb + t * 16 + l15) * 8;
            b[t][0] = bp[quad];
            b[t][1] = bp[quad + 4];
            wq[t]   = wsq_s[colb + t * 16 + l15];
        }

        #pragma unroll
        for (int mf = 0; mf < 2; ++mf) {
            floatx4 acc[4];
            #pragma unroll
            for (int t = 0; t < 4; ++t) {
                acc[t] = floatx4{0.f, 0.f, 0.f, 0.f};
                acc[t] = __builtin_amdgcn_mfma_f32_16x16x32_bf16(a[mf][0], b[t][0], acc[t], 0, 0, 0);
                acc[t] = __builtin_amdgcn_mfma_f32_16x16x32_bf16(a[mf][1], b[t][1], acc[t], 0, 0, 0);
            }

            // stage 16 rows x 64 cols to wave-private LDS
            // C/D layout (verified): row = quad*4 + i, col = t*16 + l15
            #pragma unroll
            for (int t = 0; t < 4; ++t)
                #pragma unroll
                for (int i = 0; i < 4; ++i)
                    stw[(quad * 4 + i) * STRIDE + t * 16 + l15] =
                        xs[mf][i] + wq[t] - 2.0f * acc[t][i];

            // readback + coalesced stores (DS ops in-order within a wave:
            // no barrier needed for wave-private write->read)
            #pragma unroll
            for (int j = 0; j < 4; ++j) {
                const int r = quad + 4 * j;    // 16 rows over j
                const floatx4 v = *(const floatx4*)&stw[r * STRIDE + l15 * 4];
                float* dst = out + (size_t)(row0 + mrow + mf * 16 + r) * UNITS
                                 + colb + l15 * 4;
                *(floatx4*)dst = v;            // PLAIN store — the A/B variable
            }
        }
    }
}

extern "C" void kernel_launch(void* const* d_in, const int* in_sizes, int n_in,
                              void* d_out, int out_size, void* d_ws, size_t ws_size,
                              hipStream_t stream) {
    const float* x = (const float*)d_in[0];
    const float* w = (const float*)d_in[1];
    float* out = (float*)d_out;

    unsigned short* wb  = (unsigned short*)d_ws;                       // 64 KB
    float*          wsq = (float*)((char*)d_ws + UNITS * DIM * 2);     // 2 KB

    prep_w_kernel<<<UNITS / 4, 256, 0, stream>>>(w, wb, wsq);
    dist_kernel<<<BATCH / BM, 256, 0, stream>>>(x, wb, wsq, out);
}